// Round 11
// baseline (156.484 us; speedup 1.0000x reference)
//
#include <hip/hip_runtime.h>
#include <stdint.h>

// Dims fixed by reference: x [T=4,B=32,C=196,N=768] fp32; w1,w2,w3 [768][768] fp32.
#define T_STEPS 4
#define BC      6272            // B*C
#define NDIM    768
#define TBC     (T_STEPS*BC)    // 25088
#define BCN     (BC*NDIM)
#define FIX_CAP 65536
#define MASKW   (TBC * 24)      // 24 u32 words of spike bits per row

typedef unsigned short u16;
typedef __attribute__((ext_vector_type(8))) __bf16 bf16x8;
typedef __attribute__((ext_vector_type(4))) float f32x4;
typedef __attribute__((ext_vector_type(4))) int   i32x4;

#define MFMAI8(a,b,c)  __builtin_amdgcn_mfma_i32_16x16x64_i8((a),(b),(c),0,0,0)

__device__ __forceinline__ u16 f2b(float f) {           // fp32 -> bf16 bits, RNE
    uint32_t u = __builtin_bit_cast(uint32_t, f);
    u += 0x7FFFu + ((u >> 16) & 1u);
    return (u16)(u >> 16);
}
__device__ __forceinline__ float b2f(u16 b) {
    uint32_t u = ((uint32_t)b) << 16;
    return __builtin_bit_cast(float, u);
}
__device__ __forceinline__ void gload16(const void* g, void* l) {
    __builtin_amdgcn_global_load_lds((const __attribute__((address_space(1))) void*)g,
                                     (__attribute__((address_space(3))) void*)l,
                                     16, 0, 0);
}

// ---------------------------------------------------------------------------
// Fused front-end: blocks [0,1568) run lif(x)+counts; blocks [1568,3872):
// weight prep (w1->i8 x512; w2-> two i8 limbs; w3 -> TRANSPOSED bf16 w3T)
// + zero the rowmask and fixup counter.
// ---------------------------------------------------------------------------
__global__ __launch_bounds__(256) void front_kernel(
    const float* __restrict__ x,
    const float* __restrict__ w1, const float* __restrict__ w2,
    const float* __restrict__ w3,
    int8_t* __restrict__ s8, u16* __restrict__ cnt,
    int8_t* __restrict__ w1q, int8_t* __restrict__ w2h,
    int8_t* __restrict__ w2l, u16* __restrict__ w3T,
    uint32_t* __restrict__ rowmask, uint32_t* __restrict__ fix_cnt)
{
    if (blockIdx.x < BC / 4) {
        // ---- LIF over x (fp64) + per-(t,bc) spike counts ----
        const int bc   = blockIdx.x * 4 + (threadIdx.x >> 6);
        const int lane = threadIdx.x & 63;
        const size_t base = (size_t)bc * NDIM + lane * 12;

        double v[12];
        #pragma unroll
        for (int j = 0; j < 12; ++j) v[j] = 0.0;
        uint32_t c01 = 0, c23 = 0;

        #pragma unroll
        for (int t = 0; t < T_STEPS; ++t) {
            float4 xa = *(const float4*)&x[(size_t)t * BCN + base + 0];
            float4 xb = *(const float4*)&x[(size_t)t * BCN + base + 4];
            float4 xc = *(const float4*)&x[(size_t)t * BCN + base + 8];
            float xs[12] = {xa.x, xa.y, xa.z, xa.w, xb.x, xb.y, xb.z, xb.w,
                            xc.x, xc.y, xc.z, xc.w};
            uint32_t pk[3] = {0, 0, 0};
            uint32_t csum = 0;
            #pragma unroll
            for (int j = 0; j < 12; ++j) {
                v[j] = 0.5 * v[j] + (double)xs[j];
                if (v[j] >= 1.0) {
                    pk[j >> 2] |= 1u << ((j & 3) * 8);
                    csum++;
                    v[j] = 0.0;
                }
            }
            uint32_t* dst = (uint32_t*)&s8[(size_t)t * BCN + base];
            dst[0] = pk[0]; dst[1] = pk[1]; dst[2] = pk[2];
            if (t < 2) c01 += csum << (t * 16);
            else       c23 += csum << ((t - 2) * 16);
        }
        #pragma unroll
        for (int o = 32; o > 0; o >>= 1) {
            c01 += __shfl_xor(c01, o);
            c23 += __shfl_xor(c23, o);
        }
        if (lane == 0) {
            cnt[0 * BC + bc] = (u16)(c01 & 0xFFFF);
            cnt[1 * BC + bc] = (u16)(c01 >> 16);
            cnt[2 * BC + bc] = (u16)(c23 & 0xFFFF);
            cnt[3 * BC + bc] = (u16)(c23 >> 16);
        }
    } else {
        // ---- weight prep + mask zeroing ----
        int i = (blockIdx.x - BC / 4) * 256 + threadIdx.x;  // [0, 589824)
        if (i == 0) *fix_cnt = 0;
        int q1 = __float2int_rn(w1[i] * 512.0f);
        q1 = q1 > 127 ? 127 : (q1 < -127 ? -127 : q1);
        w1q[i] = (int8_t)q1;
        int q16 = __double2int_rn((double)w2[i] * 65536.0);
        int8_t lo = (int8_t)(q16 & 0xFF);
        int hi = (q16 - (int)lo) >> 8;                      // exact split
        w2h[i] = (int8_t)hi;
        w2l[i] = lo;
        // transposed w3: coalesced write, gathered (L2-cached) read
        w3T[i] = f2b(w3[(size_t)(i % NDIM) * NDIM + (i / NDIM)]);
        // zero spike bitmask (602,112 words with 589,824 threads)
        rowmask[i] = 0;
        if (i < MASKW - NDIM * NDIM) rowmask[NDIM * NDIM + i] = 0;
    }
}

// ---------------------------------------------------------------------------
// Kernel B (i8) — round-5 GEMM core (empirical best):
// y1 = s@w1q^T, y2 = s@(w2h,w2l)^T exact i32; fp64 LIF on y2 with hard
// margin -> fixup list. NEW epilogue: sparse z writes + spike bitmask
// (no dense z). Flagged pairs defer entirely to fixup.
// ---------------------------------------------------------------------------
__global__ __launch_bounds__(256) void y12_kernel(
    const int8_t* __restrict__ s8,
    const int8_t* __restrict__ w1q, const int8_t* __restrict__ w2hb,
    const int8_t* __restrict__ w2lb,
    const u16* __restrict__ cnt,
    u16* __restrict__ z, uint32_t* __restrict__ rowmask,
    uint32_t* __restrict__ fix_cnt,
    int2* __restrict__ fix_idx, float4* __restrict__ fix_y1)
{
    // per-buffer: A [0,16384) 128x128B; B1 [16384,24576); B2h [24576,32768);
    // B2l [32768,40960)
    __shared__ int8_t lds[2][40960];

    const int tid  = threadIdx.x;
    const int lane = tid & 63;
    const int wid  = tid >> 6;

    // XCD-chunked swizzle: nwg = 2352 = 8 * 294
    const int bid = blockIdx.x;
    const int swz = (bid & 7) * 294 + (bid >> 3);
    const int mb  = swz % (NDIM / 64);
    const int rb  = swz / (NDIM / 64);
    const int m0  = mb * 64;
    const int bc0 = rb * 32;

    // ---- staging: 40 chunks of 1KB (8 rows x 128B); 10 per wave ----
    const int srow  = lane >> 3;                       // row in 8-row chunk
    const int scolB = ((lane & 7) << 4) ^ (srow << 4); // pre-swizzled src byte col
    const int8_t* gp[10];
    int lofs[10];
    #pragma unroll
    for (int c = 0; c < 10; ++c) {
        int chunk = wid * 10 + c;
        const int8_t* g;
        int l;
        if (chunk < 16) {                              // A: 128 rows = t*32+bcl
            int gr = chunk * 8 + srow;
            int t = gr >> 5, bcl = gr & 31;
            g = s8 + ((size_t)(t * BC + bc0 + bcl)) * NDIM + scolB;
            l = chunk * 1024;
        } else if (chunk < 24) {
            int mr = (chunk - 16) * 8 + srow;
            g = w1q + ((size_t)(m0 + mr)) * NDIM + scolB;
            l = 16384 + (chunk - 16) * 1024;
        } else if (chunk < 32) {
            int mr = (chunk - 24) * 8 + srow;
            g = w2hb + ((size_t)(m0 + mr)) * NDIM + scolB;
            l = 24576 + (chunk - 24) * 1024;
        } else {
            int mr = (chunk - 32) * 8 + srow;
            g = w2lb + ((size_t)(m0 + mr)) * NDIM + scolB;
            l = 32768 + (chunk - 32) * 1024;
        }
        gp[c] = g;
        lofs[c] = l;
    }

    // ---- fragment read offsets ----
    const int key = lane & 7;
    const int g4  = lane >> 4;                         // k-group 0..3
    int slotA[2];
    slotA[0] = ((g4     ^ key) << 4);                  // ks=0: slots 0..3
    slotA[1] = (((4|g4) ^ key) << 4);                  // ks=1: slots 4..7
    int abase[8];
    #pragma unroll
    for (int t = 0; t < 4; ++t)
        #pragma unroll
        for (int rt = 0; rt < 2; ++rt)
            abase[t * 2 + rt] = (t * 32 + rt * 16 + (lane & 15)) * 128;
    const int bbase = (wid * 16 + (lane & 15)) * 128;

    i32x4 acc1[4][2], acch[4][2], accl[4][2];
    #pragma unroll
    for (int t = 0; t < 4; ++t)
        #pragma unroll
        for (int rt = 0; rt < 2; ++rt) {
            acc1[t][rt] = (i32x4){0, 0, 0, 0};
            acch[t][rt] = (i32x4){0, 0, 0, 0};
            accl[t][rt] = (i32x4){0, 0, 0, 0};
        }

    auto stage = [&](int buf) {
        #pragma unroll
        for (int c = 0; c < 10; ++c) {
            gload16(gp[c], &lds[buf][lofs[c]]);
            gp[c] += 128;
        }
    };
    auto compute = [&](int buf) {
        const int8_t* L = lds[buf];
        #pragma unroll
        for (int ks = 0; ks < 2; ++ks) {
            const int sl = slotA[ks];
            i32x4 b1 = *(const i32x4*)&L[16384 + bbase + sl];
            i32x4 bh = *(const i32x4*)&L[24576 + bbase + sl];
            i32x4 bl = *(const i32x4*)&L[32768 + bbase + sl];
            #pragma unroll
            for (int t = 0; t < 4; ++t)
                #pragma unroll
                for (int rt = 0; rt < 2; ++rt) {
                    i32x4 a = *(const i32x4*)&L[abase[t * 2 + rt] + sl];
                    acc1[t][rt] = MFMAI8(a, b1, acc1[t][rt]);
                    acch[t][rt] = MFMAI8(a, bh, acch[t][rt]);
                    accl[t][rt] = MFMAI8(a, bl, accl[t][rt]);
                }
        }
    };

    // ---- 2-phase dbuf over 6 K-128 tiles ----
    stage(0);
    __syncthreads();
    #pragma unroll
    for (int it = 0; it < 5; ++it) {
        stage((it + 1) & 1);
        compute(it & 1);
        __syncthreads();
    }
    compute(1);

    // ---- epilogue: exact y2_q, fp64 LIF with hard margin.
    //      Non-flagged: write z + set spike bit only where spiking.
    //      Flagged: defer entirely to fixup. ----
    const int mg = m0 + wid * 16 + (lane & 15);
    #pragma unroll
    for (int rt = 0; rt < 2; ++rt) {
        #pragma unroll
        for (int r = 0; r < 4; ++r) {
            const int bcg = bc0 + rt * 16 + (lane >> 4) * 4 + r;
            double v = 0.0, e = 0.0;
            bool flag = false;
            int sp = 0;
            float zv[4], y1v[4];
            #pragma unroll
            for (int t = 0; t < 4; ++t) {
                float y1 = (float)acc1[t][rt][r] * (1.0f / 512.0f);
                y1v[t] = y1;
                double y2 = (double)(acch[t][rt][r] * 256 + accl[t][rt][r])
                            * (1.0 / 65536.0);
                v = 0.5 * v + y2;
                e = 0.5 * e + 7.62939453125e-6 * (double)cnt[t * BC + bcg] + 1e-9;
                double d = v - 1.0;
                flag |= (d <= e && d >= -e);
                if (v >= 1.0) { zv[t] = y1; sp |= 1 << t; v = 0.0; e = 0.0; }
                else          { zv[t] = 0.0f; }
            }
            if (flag) {
                uint32_t id = atomicAdd(fix_cnt, 1u);
                if (id < FIX_CAP) {
                    fix_idx[id] = make_int2(bcg, mg);
                    fix_y1[id]  = make_float4(y1v[0], y1v[1], y1v[2], y1v[3]);
                }
            } else if (sp) {
                #pragma unroll
                for (int t = 0; t < 4; ++t)
                    if ((sp >> t) & 1) {
                        int row = t * BC + bcg;
                        z[(size_t)row * NDIM + mg] = f2b(zv[t]);
                        atomicOr(&rowmask[(size_t)row * 24 + (mg >> 5)],
                                 1u << (mg & 31));
                    }
            }
        }
    }
}

// ---------------------------------------------------------------------------
// Exact fp64 recompute of flagged (bc,m) pairs; one wave per entry.
// Writes z + spike bits for its spiking t's.
// ---------------------------------------------------------------------------
__global__ __launch_bounds__(256) void fixup_kernel(
    const int8_t* __restrict__ s8, const float* __restrict__ w2,
    const int2* __restrict__ fix_idx, const float4* __restrict__ fix_y1,
    const uint32_t* __restrict__ fix_cnt,
    u16* __restrict__ z, uint32_t* __restrict__ rowmask)
{
    const int lane = threadIdx.x & 63;
    const int wave = (blockIdx.x * 256 + threadIdx.x) >> 6;
    const int nw   = gridDim.x * 4;
    uint32_t n = *fix_cnt;
    if (n > FIX_CAP) n = FIX_CAP;

    for (uint32_t e = wave; e < n; e += nw) {
        const int bc = fix_idx[e].x, m = fix_idx[e].y;
        const float* w2row = w2 + (size_t)m * NDIM;
        double acc[4] = {0.0, 0.0, 0.0, 0.0};
        #pragma unroll
        for (int j = 0; j < NDIM / 64; ++j) {
            int nn = lane + j * 64;
            double wv = (double)w2row[nn];
            #pragma unroll
            for (int t = 0; t < 4; ++t)
                if (s8[((size_t)(t * BC + bc)) * NDIM + nn]) acc[t] += wv;
        }
        #pragma unroll
        for (int o = 32; o > 0; o >>= 1)
            #pragma unroll
            for (int t = 0; t < 4; ++t) acc[t] += __shfl_xor(acc[t], o);
        if (lane == 0) {
            float4 y1 = fix_y1[e];
            float y1a[4] = {y1.x, y1.y, y1.z, y1.w};
            double v = 0.0;
            #pragma unroll
            for (int t = 0; t < 4; ++t) {
                v = 0.5 * v + acc[t];
                if (v >= 1.0) {
                    int row = t * BC + bc;
                    z[(size_t)row * NDIM + m] = f2b(y1a[t]);
                    atomicOr(&rowmask[(size_t)row * 24 + (m >> 5)],
                             1u << (m & 31));
                    v = 0.0;
                }
            }
        }
    }
}

// ---------------------------------------------------------------------------
// Kernel C (sparse): out[r][:] = sum over spiking m of z[r][m] * w3T[m][:].
// One wave per row (z rows are ~98.5% empty, ~11.6 nonzeros each).
// Deterministic: bits iterated in ascending m. Floor = 77MB fp32 out-write.
// ---------------------------------------------------------------------------
__global__ __launch_bounds__(256) void out_sparse_kernel(
    const u16* __restrict__ z, const u16* __restrict__ w3T,
    const uint32_t* __restrict__ rowmask, float* __restrict__ out)
{
    const int r    = blockIdx.x * 4 + (threadIdx.x >> 6);
    const int lane = threadIdx.x & 63;
    const int base = lane * 4;

    f32x4 a0 = {0.f, 0.f, 0.f, 0.f};
    f32x4 a1 = {0.f, 0.f, 0.f, 0.f};
    f32x4 a2 = {0.f, 0.f, 0.f, 0.f};

    const uint32_t* mw = rowmask + (size_t)r * 24;
    #pragma unroll 4
    for (int w = 0; w < 24; ++w) {
        uint32_t bits = mw[w];
        while (bits) {
            int b = __ffs(bits) - 1;
            bits &= bits - 1;
            int m = w * 32 + b;
            float val = b2f(z[(size_t)r * NDIM + m]);
            const u16* wr = &w3T[(size_t)m * NDIM + base];
            ushort4 q0 = *(const ushort4*)&wr[0];
            ushort4 q1 = *(const ushort4*)&wr[256];
            ushort4 q2 = *(const ushort4*)&wr[512];
            a0[0] += val * b2f(q0.x); a0[1] += val * b2f(q0.y);
            a0[2] += val * b2f(q0.z); a0[3] += val * b2f(q0.w);
            a1[0] += val * b2f(q1.x); a1[1] += val * b2f(q1.y);
            a1[2] += val * b2f(q1.z); a1[3] += val * b2f(q1.w);
            a2[0] += val * b2f(q2.x); a2[1] += val * b2f(q2.y);
            a2[2] += val * b2f(q2.z); a2[3] += val * b2f(q2.w);
        }
    }
    float* orow = out + (size_t)r * NDIM + base;
    *(f32x4*)&orow[0]   = a0;
    *(f32x4*)&orow[256] = a1;
    *(f32x4*)&orow[512] = a2;
}

// ---------------------------------------------------------------------------
extern "C" void kernel_launch(void* const* d_in, const int* in_sizes, int n_in,
                              void* d_out, int out_size, void* d_ws, size_t ws_size,
                              hipStream_t stream) {
    const float* x  = (const float*)d_in[0];
    const float* w1 = (const float*)d_in[1];
    const float* w2 = (const float*)d_in[2];
    const float* w3 = (const float*)d_in[3];
    float* out = (float*)d_out;

    char* ws = (char*)d_ws;
    int8_t*   s8      = (int8_t*)(ws);                    // 19,267,584
    u16*      z       = (u16*)(ws + 19267584);            // 38,535,168
    int8_t*   w1q     = (int8_t*)(ws + 57802752);         //    589,824
    int8_t*   w2h     = (int8_t*)(ws + 58392576);         //    589,824
    int8_t*   w2l     = (int8_t*)(ws + 58982400);         //    589,824
    u16*      w3T     = (u16*)(ws + 59572224);            //  1,179,648
    u16*      cnt     = (u16*)(ws + 60751872);            //     50,176
    uint32_t* fix_cnt = (uint32_t*)(ws + 60802048);       //         64
    int2*     fix_idx = (int2*)(ws + 60802112);           //    524,288
    float4*   fix_y1  = (float4*)(ws + 61326400);         //  1,048,576
    uint32_t* rowmask = (uint32_t*)(ws + 62374976);       //  2,408,448

    front_kernel<<<BC / 4 + (NDIM * NDIM) / 256, 256, 0, stream>>>(
        x, w1, w2, w3, s8, cnt, w1q, w2h, w2l, w3T, rowmask, fix_cnt);
    y12_kernel<<<(BC / 32) * (NDIM / 64), 256, 0, stream>>>(
        s8, w1q, w2h, w2l, cnt, z, rowmask, fix_cnt, fix_idx, fix_y1);
    fixup_kernel<<<512, 256, 0, stream>>>(s8, w2, fix_idx, fix_y1, fix_cnt,
                                          z, rowmask);
    out_sparse_kernel<<<TBC / 4, 256, 0, stream>>>(z, w3T, rowmask, out);
}

// Round 12
// 147.302 us; speedup vs baseline: 1.0623x; 1.0623x over previous
//
#include <hip/hip_runtime.h>
#include <stdint.h>

// Dims fixed by reference: x [T=4,B=32,C=196,N=768] fp32; w1,w2,w3 [768][768] fp32.
#define T_STEPS 4
#define BC      6272            // B*C
#define NDIM    768
#define TBC     (T_STEPS*BC)    // 25088
#define BCN     (BC*NDIM)
#define FIX_CAP 65536

typedef unsigned short u16;
typedef __attribute__((ext_vector_type(4))) float f32x4;
typedef __attribute__((ext_vector_type(4))) int   i32x4;

#define MFMAI8(a,b,c)  __builtin_amdgcn_mfma_i32_16x16x64_i8((a),(b),(c),0,0,0)

__device__ __forceinline__ u16 f2b(float f) {           // fp32 -> bf16 bits, RNE
    uint32_t u = __builtin_bit_cast(uint32_t, f);
    u += 0x7FFFu + ((u >> 16) & 1u);
    return (u16)(u >> 16);
}
__device__ __forceinline__ float b2f(u16 b) {
    uint32_t u = ((uint32_t)b) << 16;
    return __builtin_bit_cast(float, u);
}
__device__ __forceinline__ void gload16(const void* g, void* l) {
    __builtin_amdgcn_global_load_lds((const __attribute__((address_space(1))) void*)g,
                                     (__attribute__((address_space(3))) void*)l,
                                     16, 0, 0);
}

// ---------------------------------------------------------------------------
// Fused front-end: blocks [0,1568) run lif(x)+counts; blocks [1568,3872):
// weight prep (w1->i8 x512; w2-> two i8 limbs; w3 -> transposed bf16 w3T).
// ---------------------------------------------------------------------------
__global__ __launch_bounds__(256) void front_kernel(
    const float* __restrict__ x,
    const float* __restrict__ w1, const float* __restrict__ w2,
    const float* __restrict__ w3,
    int8_t* __restrict__ s8, u16* __restrict__ cnt,
    int8_t* __restrict__ w1q, int8_t* __restrict__ w2h,
    int8_t* __restrict__ w2l, u16* __restrict__ w3T,
    uint32_t* __restrict__ fix_cnt)
{
    if (blockIdx.x < BC / 4) {
        // ---- LIF over x (fp64) + per-(t,bc) spike counts ----
        const int bc   = blockIdx.x * 4 + (threadIdx.x >> 6);
        const int lane = threadIdx.x & 63;
        const size_t base = (size_t)bc * NDIM + lane * 12;

        double v[12];
        #pragma unroll
        for (int j = 0; j < 12; ++j) v[j] = 0.0;
        uint32_t c01 = 0, c23 = 0;

        #pragma unroll
        for (int t = 0; t < T_STEPS; ++t) {
            float4 xa = *(const float4*)&x[(size_t)t * BCN + base + 0];
            float4 xb = *(const float4*)&x[(size_t)t * BCN + base + 4];
            float4 xc = *(const float4*)&x[(size_t)t * BCN + base + 8];
            float xs[12] = {xa.x, xa.y, xa.z, xa.w, xb.x, xb.y, xb.z, xb.w,
                            xc.x, xc.y, xc.z, xc.w};
            uint32_t pk[3] = {0, 0, 0};
            uint32_t csum = 0;
            #pragma unroll
            for (int j = 0; j < 12; ++j) {
                v[j] = 0.5 * v[j] + (double)xs[j];
                if (v[j] >= 1.0) {
                    pk[j >> 2] |= 1u << ((j & 3) * 8);
                    csum++;
                    v[j] = 0.0;
                }
            }
            uint32_t* dst = (uint32_t*)&s8[(size_t)t * BCN + base];
            dst[0] = pk[0]; dst[1] = pk[1]; dst[2] = pk[2];
            if (t < 2) c01 += csum << (t * 16);
            else       c23 += csum << ((t - 2) * 16);
        }
        #pragma unroll
        for (int o = 32; o > 0; o >>= 1) {
            c01 += __shfl_xor(c01, o);
            c23 += __shfl_xor(c23, o);
        }
        if (lane == 0) {
            cnt[0 * BC + bc] = (u16)(c01 & 0xFFFF);
            cnt[1 * BC + bc] = (u16)(c01 >> 16);
            cnt[2 * BC + bc] = (u16)(c23 & 0xFFFF);
            cnt[3 * BC + bc] = (u16)(c23 >> 16);
        }
    } else {
        // ---- weight prep ----
        int i = (blockIdx.x - BC / 4) * 256 + threadIdx.x;  // [0, 589824)
        if (i == 0) *fix_cnt = 0;
        int q1 = __float2int_rn(w1[i] * 512.0f);
        q1 = q1 > 127 ? 127 : (q1 < -127 ? -127 : q1);
        w1q[i] = (int8_t)q1;
        int q16 = __double2int_rn((double)w2[i] * 65536.0);
        int8_t lo = (int8_t)(q16 & 0xFF);
        int hi = (q16 - (int)lo) >> 8;                      // exact split
        w2h[i] = (int8_t)hi;
        w2l[i] = lo;
        // transposed w3: w3T[n][m] = w3[m][n]
        w3T[i] = f2b(w3[(size_t)(i % NDIM) * NDIM + (i / NDIM)]);
    }
}

// ---------------------------------------------------------------------------
// y12 V1 — round-10 verbatim (K-128 tiles, 2x40KB LDS, 2 blocks/CU).
// Handles rb in [rb_base, rb_base+98).
// ---------------------------------------------------------------------------
__global__ __launch_bounds__(256) void y12_v1(
    const int8_t* __restrict__ s8,
    const int8_t* __restrict__ w1q, const int8_t* __restrict__ w2hb,
    const int8_t* __restrict__ w2lb,
    const u16* __restrict__ cnt,
    u16* __restrict__ z,
    uint32_t* __restrict__ fix_cnt,
    int2* __restrict__ fix_idx, float4* __restrict__ fix_y1,
    int rb_base)
{
    __shared__ int8_t lds[2][40960];

    const int lane = threadIdx.x & 63;
    const int wid  = threadIdx.x >> 6;

    // XCD-chunked swizzle: nwg = 1176 = 8 * 147
    const int bid = blockIdx.x;
    const int swz = (bid & 7) * 147 + (bid >> 3);
    const int mb  = swz % (NDIM / 64);
    const int rb  = rb_base + swz / (NDIM / 64);
    const int m0  = mb * 64;
    const int bc0 = rb * 32;

    const int srow  = lane >> 3;
    const int scolB = ((lane & 7) << 4) ^ (srow << 4);
    const int8_t* gp[10];
    int lofs[10];
    #pragma unroll
    for (int c = 0; c < 10; ++c) {
        int chunk = wid * 10 + c;
        const int8_t* g;
        int l;
        if (chunk < 16) {
            int gr = chunk * 8 + srow;
            int t = gr >> 5, bcl = gr & 31;
            g = s8 + ((size_t)(t * BC + bc0 + bcl)) * NDIM + scolB;
            l = chunk * 1024;
        } else if (chunk < 24) {
            int mr = (chunk - 16) * 8 + srow;
            g = w1q + ((size_t)(m0 + mr)) * NDIM + scolB;
            l = 16384 + (chunk - 16) * 1024;
        } else if (chunk < 32) {
            int mr = (chunk - 24) * 8 + srow;
            g = w2hb + ((size_t)(m0 + mr)) * NDIM + scolB;
            l = 24576 + (chunk - 24) * 1024;
        } else {
            int mr = (chunk - 32) * 8 + srow;
            g = w2lb + ((size_t)(m0 + mr)) * NDIM + scolB;
            l = 32768 + (chunk - 32) * 1024;
        }
        gp[c] = g;
        lofs[c] = l;
    }

    const int key = lane & 7;
    const int g4  = lane >> 4;
    int slotA[2];
    slotA[0] = ((g4       ^ key) << 4);
    slotA[1] = (((4 | g4) ^ key) << 4);
    int abase[8];
    #pragma unroll
    for (int t = 0; t < 4; ++t)
        #pragma unroll
        for (int rt = 0; rt < 2; ++rt)
            abase[t * 2 + rt] = (t * 32 + rt * 16 + (lane & 15)) * 128;
    const int bbase = (wid * 16 + (lane & 15)) * 128;

    i32x4 acc1[4][2], acch[4][2], accl[4][2];
    #pragma unroll
    for (int t = 0; t < 4; ++t)
        #pragma unroll
        for (int rt = 0; rt < 2; ++rt) {
            acc1[t][rt] = (i32x4){0, 0, 0, 0};
            acch[t][rt] = (i32x4){0, 0, 0, 0};
            accl[t][rt] = (i32x4){0, 0, 0, 0};
        }

    auto stage = [&](int buf) {
        #pragma unroll
        for (int c = 0; c < 10; ++c) {
            gload16(gp[c], &lds[buf][lofs[c]]);
            gp[c] += 128;
        }
    };
    auto compute = [&](int buf) {
        const int8_t* L = lds[buf];
        #pragma unroll
        for (int ks = 0; ks < 2; ++ks) {
            const int sl = slotA[ks];
            i32x4 b1 = *(const i32x4*)&L[16384 + bbase + sl];
            i32x4 bh = *(const i32x4*)&L[24576 + bbase + sl];
            i32x4 bl = *(const i32x4*)&L[32768 + bbase + sl];
            #pragma unroll
            for (int t = 0; t < 4; ++t)
                #pragma unroll
                for (int rt = 0; rt < 2; ++rt) {
                    i32x4 a = *(const i32x4*)&L[abase[t * 2 + rt] + sl];
                    acc1[t][rt] = MFMAI8(a, b1, acc1[t][rt]);
                    acch[t][rt] = MFMAI8(a, bh, acch[t][rt]);
                    accl[t][rt] = MFMAI8(a, bl, accl[t][rt]);
                }
        }
    };

    stage(0);
    __syncthreads();
    #pragma unroll
    for (int it = 0; it < 5; ++it) {
        stage((it + 1) & 1);
        compute(it & 1);
        __syncthreads();
    }
    compute(1);

    const int mg = m0 + wid * 16 + (lane & 15);
    #pragma unroll
    for (int rt = 0; rt < 2; ++rt) {
        #pragma unroll
        for (int r = 0; r < 4; ++r) {
            const int bcg = bc0 + rt * 16 + (lane >> 4) * 4 + r;
            double v = 0.0, e = 0.0;
            bool flag = false;
            float zv[4], y1v[4];
            #pragma unroll
            for (int t = 0; t < 4; ++t) {
                float y1 = (float)acc1[t][rt][r] * (1.0f / 512.0f);
                y1v[t] = y1;
                double y2 = (double)(acch[t][rt][r] * 256 + accl[t][rt][r])
                            * (1.0 / 65536.0);
                v = 0.5 * v + y2;
                e = 0.5 * e + 7.62939453125e-6 * (double)cnt[t * BC + bcg] + 1e-9;
                double d = v - 1.0;
                flag |= (d <= e && d >= -e);
                if (v >= 1.0) { zv[t] = y1; v = 0.0; e = 0.0; }
                else          { zv[t] = 0.0f; }
            }
            if (flag) {
                uint32_t id = atomicAdd(fix_cnt, 1u);
                if (id < FIX_CAP) {
                    fix_idx[id] = make_int2(bcg, mg);
                    fix_y1[id]  = make_float4(y1v[0], y1v[1], y1v[2], y1v[3]);
                }
            }
            #pragma unroll
            for (int t = 0; t < 4; ++t)
                z[((size_t)(t * BC + bcg)) * NDIM + mg] = f2b(zv[t]);
        }
    }
}

// ---------------------------------------------------------------------------
// y12 V2 — K-64 tiles, 2x20KB LDS (40KB total -> 4 blocks/CU), same geometry
// (bc 32 x m 64, 4 waves), NO forced launch_bounds (r8's spill fix).
// Handles rb in [rb_base, rb_base+98).
// ---------------------------------------------------------------------------
__global__ __launch_bounds__(256) void y12_v2(
    const int8_t* __restrict__ s8,
    const int8_t* __restrict__ w1q, const int8_t* __restrict__ w2hb,
    const int8_t* __restrict__ w2lb,
    const u16* __restrict__ cnt,
    u16* __restrict__ z,
    uint32_t* __restrict__ fix_cnt,
    int2* __restrict__ fix_idx, float4* __restrict__ fix_y1,
    int rb_base)
{
    // per-buffer (20480 B): A [0,8192) 128 rows x 64B; B1 [8192,12288);
    // B2h [12288,16384); B2l [16384,20480)
    __shared__ int8_t lds[2][20480];

    const int lane = threadIdx.x & 63;
    const int wid  = threadIdx.x >> 6;

    const int bid = blockIdx.x;                        // nwg 1176 = 8*147
    const int swz = (bid & 7) * 147 + (bid >> 3);
    const int mb  = swz % (NDIM / 64);
    const int rb  = rb_base + swz / (NDIM / 64);
    const int m0  = mb * 64;
    const int bc0 = rb * 32;

    // staging: 20 chunks of 1KB (16 rows x 64B); 5 per wave
    const int srow  = lane >> 2;
    const int scolB = ((lane & 3) ^ ((lane >> 3) & 3)) << 4;
    const int8_t* gp[5];
    int lofs[5];
    #pragma unroll
    for (int c = 0; c < 5; ++c) {
        int chunk = wid * 5 + c;
        const int8_t* g;
        int l;
        if (chunk < 8) {                               // A: 128 rows = t*32+bcl
            int gr = chunk * 16 + srow;
            int t = gr >> 5, bcl = gr & 31;
            g = s8 + ((size_t)(t * BC + bc0 + bcl)) * NDIM + scolB;
            l = chunk * 1024;
        } else if (chunk < 12) {
            int mr = (chunk - 8) * 16 + srow;
            g = w1q + ((size_t)(m0 + mr)) * NDIM + scolB;
            l = 8192 + (chunk - 8) * 1024;
        } else if (chunk < 16) {
            int mr = (chunk - 12) * 16 + srow;
            g = w2hb + ((size_t)(m0 + mr)) * NDIM + scolB;
            l = 12288 + (chunk - 12) * 1024;
        } else {
            int mr = (chunk - 16) * 16 + srow;
            g = w2lb + ((size_t)(m0 + mr)) * NDIM + scolB;
            l = 16384 + (chunk - 16) * 1024;
        }
        gp[c] = g;
        lofs[c] = l;
    }

    // fragment read offsets: slot swizzle keyed on (row>>1)&3
    const int slotb = (((lane >> 4) ^ ((lane >> 1) & 3)) << 4);
    int aoff[4][2];
    #pragma unroll
    for (int t = 0; t < 4; ++t)
        #pragma unroll
        for (int rt = 0; rt < 2; ++rt)
            aoff[t][rt] = (t * 32 + rt * 16 + (lane & 15)) * 64 + slotb;
    const int boff = (wid * 16 + (lane & 15)) * 64 + slotb;

    i32x4 a1[4][2], ah[4][2], al[4][2];
    #pragma unroll
    for (int t = 0; t < 4; ++t)
        #pragma unroll
        for (int rt = 0; rt < 2; ++rt) {
            a1[t][rt] = (i32x4){0, 0, 0, 0};
            ah[t][rt] = (i32x4){0, 0, 0, 0};
            al[t][rt] = (i32x4){0, 0, 0, 0};
        }

    auto stage = [&](int buf) {
        #pragma unroll
        for (int c = 0; c < 5; ++c) {
            gload16(gp[c], &lds[buf][lofs[c]]);
            gp[c] += 64;                               // next K-64 tile
        }
    };
    auto compute = [&](int buf) {
        const int8_t* L = lds[buf];
        i32x4 b1 = *(const i32x4*)&L[ 8192 + boff];
        i32x4 bh = *(const i32x4*)&L[12288 + boff];
        i32x4 bl = *(const i32x4*)&L[16384 + boff];
        #pragma unroll
        for (int t = 0; t < 4; ++t)
            #pragma unroll
            for (int rt = 0; rt < 2; ++rt) {
                i32x4 a = *(const i32x4*)&L[aoff[t][rt]];
                a1[t][rt] = MFMAI8(a, b1, a1[t][rt]);
                ah[t][rt] = MFMAI8(a, bh, ah[t][rt]);
                al[t][rt] = MFMAI8(a, bl, al[t][rt]);
            }
    };

    stage(0);
    __syncthreads();
    for (int it = 0; it < 11; ++it) {
        stage((it + 1) & 1);
        compute(it & 1);
        __syncthreads();
    }
    compute(1);

    const int mg = m0 + wid * 16 + (lane & 15);
    #pragma unroll
    for (int rt = 0; rt < 2; ++rt) {
        #pragma unroll
        for (int r = 0; r < 4; ++r) {
            const int bcg = bc0 + rt * 16 + (lane >> 4) * 4 + r;
            double v = 0.0, e = 0.0;
            bool flag = false;
            float zv[4], y1v[4];
            #pragma unroll
            for (int t = 0; t < 4; ++t) {
                float y1 = (float)a1[t][rt][r] * (1.0f / 512.0f);
                y1v[t] = y1;
                double y2 = (double)(ah[t][rt][r] * 256 + al[t][rt][r])
                            * (1.0 / 65536.0);
                v = 0.5 * v + y2;
                e = 0.5 * e + 7.62939453125e-6 * (double)cnt[t * BC + bcg] + 1e-9;
                double d = v - 1.0;
                flag |= (d <= e && d >= -e);
                if (v >= 1.0) { zv[t] = y1; v = 0.0; e = 0.0; }
                else          { zv[t] = 0.0f; }
            }
            if (flag) {
                uint32_t id = atomicAdd(fix_cnt, 1u);
                if (id < FIX_CAP) {
                    fix_idx[id] = make_int2(bcg, mg);
                    fix_y1[id]  = make_float4(y1v[0], y1v[1], y1v[2], y1v[3]);
                }
            }
            #pragma unroll
            for (int t = 0; t < 4; ++t)
                z[((size_t)(t * BC + bcg)) * NDIM + mg] = f2b(zv[t]);
        }
    }
}

// ---------------------------------------------------------------------------
// Exact fp64 recompute of flagged (bc,m) pairs; one wave per entry.
// Writes all 4 t's (full correction of the provisional epilogue values).
// ---------------------------------------------------------------------------
__global__ __launch_bounds__(256) void fixup_kernel(
    const int8_t* __restrict__ s8, const float* __restrict__ w2,
    const int2* __restrict__ fix_idx, const float4* __restrict__ fix_y1,
    const uint32_t* __restrict__ fix_cnt, u16* __restrict__ z)
{
    const int lane = threadIdx.x & 63;
    const int wave = (blockIdx.x * 256 + threadIdx.x) >> 6;
    const int nw   = gridDim.x * 4;
    uint32_t n = *fix_cnt;
    if (n > FIX_CAP) n = FIX_CAP;

    for (uint32_t e = wave; e < n; e += nw) {
        const int bc = fix_idx[e].x, m = fix_idx[e].y;
        const float* w2row = w2 + (size_t)m * NDIM;
        double acc[4] = {0.0, 0.0, 0.0, 0.0};
        #pragma unroll
        for (int j = 0; j < NDIM / 64; ++j) {
            int nn = lane + j * 64;
            double wv = (double)w2row[nn];
            #pragma unroll
            for (int t = 0; t < 4; ++t)
                if (s8[((size_t)(t * BC + bc)) * NDIM + nn]) acc[t] += wv;
        }
        #pragma unroll
        for (int o = 32; o > 0; o >>= 1)
            #pragma unroll
            for (int t = 0; t < 4; ++t) acc[t] += __shfl_xor(acc[t], o);
        if (lane == 0) {
            float4 y1 = fix_y1[e];
            float y1a[4] = {y1.x, y1.y, y1.z, y1.w};
            double v = 0.0;
            #pragma unroll
            for (int t = 0; t < 4; ++t) {
                v = 0.5 * v + acc[t];
                u16 zz = 0;
                if (v >= 1.0) { zz = f2b(y1a[t]); v = 0.0; }
                z[((size_t)(t * BC + bc)) * NDIM + m] = zz;
            }
        }
    }
}

// ---------------------------------------------------------------------------
// Kernel C (ballot-sparse): out[r][:] = sum_{m: z[r][m]!=0} z[r][m]*w3T[m][:].
// One wave per row. Dense coalesced z read, no precomputed mask, no atomics.
// Bits iterated in ascending m -> deterministic. Lane owns out[r][lane*12..+12).
// ---------------------------------------------------------------------------
__global__ __launch_bounds__(256) void out_sparse_kernel(
    const u16* __restrict__ z, const u16* __restrict__ w3T,
    float* __restrict__ out)
{
    const int r    = blockIdx.x * 4 + (threadIdx.x >> 6);
    const int lane = threadIdx.x & 63;

    float acc[12];
    #pragma unroll
    for (int k = 0; k < 12; ++k) acc[k] = 0.0f;

    const u16* zr = z + (size_t)r * NDIM;
    #pragma unroll
    for (int j = 0; j < 12; ++j) {
        u16 zb = zr[j * 64 + lane];
        float zval = b2f(zb);
        unsigned long long bits = __ballot(zb != 0);
        while (bits) {
            int b = __ffsll(bits) - 1;
            bits &= bits - 1;
            float v = __shfl(zval, b);
            int m = j * 64 + b;
            const u16* wr = w3T + (size_t)m * NDIM + lane * 12;
            ushort4 q0 = *(const ushort4*)&wr[0];
            ushort4 q1 = *(const ushort4*)&wr[4];
            ushort4 q2 = *(const ushort4*)&wr[8];
            acc[0]  = fmaf(v, b2f(q0.x), acc[0]);
            acc[1]  = fmaf(v, b2f(q0.y), acc[1]);
            acc[2]  = fmaf(v, b2f(q0.z), acc[2]);
            acc[3]  = fmaf(v, b2f(q0.w), acc[3]);
            acc[4]  = fmaf(v, b2f(q1.x), acc[4]);
            acc[5]  = fmaf(v, b2f(q1.y), acc[5]);
            acc[6]  = fmaf(v, b2f(q1.z), acc[6]);
            acc[7]  = fmaf(v, b2f(q1.w), acc[7]);
            acc[8]  = fmaf(v, b2f(q2.x), acc[8]);
            acc[9]  = fmaf(v, b2f(q2.y), acc[9]);
            acc[10] = fmaf(v, b2f(q2.z), acc[10]);
            acc[11] = fmaf(v, b2f(q2.w), acc[11]);
        }
    }
    float* orow = out + (size_t)r * NDIM + lane * 12;
    *(f32x4*)&orow[0] = (f32x4){acc[0], acc[1], acc[2],  acc[3]};
    *(f32x4*)&orow[4] = (f32x4){acc[4], acc[5], acc[6],  acc[7]};
    *(f32x4*)&orow[8] = (f32x4){acc[8], acc[9], acc[10], acc[11]};
}

// ---------------------------------------------------------------------------
extern "C" void kernel_launch(void* const* d_in, const int* in_sizes, int n_in,
                              void* d_out, int out_size, void* d_ws, size_t ws_size,
                              hipStream_t stream) {
    const float* x  = (const float*)d_in[0];
    const float* w1 = (const float*)d_in[1];
    const float* w2 = (const float*)d_in[2];
    const float* w3 = (const float*)d_in[3];
    float* out = (float*)d_out;

    char* ws = (char*)d_ws;
    int8_t*   s8      = (int8_t*)(ws);                    // 19,267,584
    u16*      z       = (u16*)(ws + 19267584);            // 38,535,168
    int8_t*   w1q     = (int8_t*)(ws + 57802752);
    int8_t*   w2h     = (int8_t*)(ws + 58392576);
    int8_t*   w2l     = (int8_t*)(ws + 58982400);
    u16*      w3T     = (u16*)(ws + 59572224);
    u16*      cnt     = (u16*)(ws + 60751872);
    uint32_t* fix_cnt = (uint32_t*)(ws + 60802048);
    int2*     fix_idx = (int2*)(ws + 60802112);
    float4*   fix_y1  = (float4*)(ws + 61326400);

    front_kernel<<<BC / 4 + (NDIM * NDIM) / 256, 256, 0, stream>>>(
        x, w1, w2, w3, s8, cnt, w1q, w2h, w2l, w3T, fix_cnt);
    // within-probe A/B: v1 (r10 structure) on rb [0,98), v2 (K-64, 40KB LDS,
    // 4 blk/CU) on rb [98,196). Each 1176 blocks (= 8*147, swizzle-exact).
    y12_v1<<<1176, 256, 0, stream>>>(s8, w1q, w2h, w2l, cnt, z, fix_cnt,
                                     fix_idx, fix_y1, 0);
    y12_v2<<<1176, 256, 0, stream>>>(s8, w1q, w2h, w2l, cnt, z, fix_cnt,
                                     fix_idx, fix_y1, 98);
    fixup_kernel<<<512, 256, 0, stream>>>(s8, w2, fix_idx, fix_y1, fix_cnt, z);
    out_sparse_kernel<<<TBC / 4, 256, 0, stream>>>(z, w3T, out);
}

// Round 13
// 122.045 us; speedup vs baseline: 1.2822x; 1.2070x over previous
//
#include <hip/hip_runtime.h>
#include <stdint.h>

// Dims fixed by reference: x [T=4,B=32,C=196,N=768] fp32; w1,w2,w3 [768][768] fp32.
#define T_STEPS 4
#define BC      6272            // B*C
#define NDIM    768
#define TBC     (T_STEPS*BC)    // 25088
#define BCN     (BC*NDIM)
#define FIX_CAP 65536

typedef unsigned short u16;
typedef __attribute__((ext_vector_type(8))) __bf16 bf16x8;
typedef __attribute__((ext_vector_type(4))) float f32x4;
typedef __attribute__((ext_vector_type(4))) int   i32x4;

#define MFMA16(a,b,c)  __builtin_amdgcn_mfma_f32_16x16x32_bf16((a),(b),(c),0,0,0)
#define MFMAI8(a,b,c)  __builtin_amdgcn_mfma_i32_16x16x64_i8((a),(b),(c),0,0,0)

__device__ __forceinline__ u16 f2b(float f) {           // fp32 -> bf16 bits, RNE
    uint32_t u = __builtin_bit_cast(uint32_t, f);
    u += 0x7FFFu + ((u >> 16) & 1u);
    return (u16)(u >> 16);
}
__device__ __forceinline__ void gload16(const void* g, void* l) {
    __builtin_amdgcn_global_load_lds((const __attribute__((address_space(1))) void*)g,
                                     (__attribute__((address_space(3))) void*)l,
                                     16, 0, 0);
}

// ---------------------------------------------------------------------------
// Fused front-end: blocks [0,1568) run lif(x)+counts; blocks [1568,3872) run
// weight prep (w1->i8 x512; w2-> two i8 limbs of round(w2*65536); w3->bf16).
// ---------------------------------------------------------------------------
__global__ __launch_bounds__(256) void front_kernel(
    const float* __restrict__ x,
    const float* __restrict__ w1, const float* __restrict__ w2,
    const float* __restrict__ w3,
    int8_t* __restrict__ s8, u16* __restrict__ cnt,
    int8_t* __restrict__ w1q, int8_t* __restrict__ w2h,
    int8_t* __restrict__ w2l, u16* __restrict__ w3b,
    uint32_t* __restrict__ fix_cnt)
{
    if (blockIdx.x < BC / 4) {
        // ---- LIF over x (fp64) + per-(t,bc) spike counts ----
        const int bc   = blockIdx.x * 4 + (threadIdx.x >> 6);
        const int lane = threadIdx.x & 63;
        const size_t base = (size_t)bc * NDIM + lane * 12;

        double v[12];
        #pragma unroll
        for (int j = 0; j < 12; ++j) v[j] = 0.0;
        uint32_t c01 = 0, c23 = 0;

        #pragma unroll
        for (int t = 0; t < T_STEPS; ++t) {
            float4 xa = *(const float4*)&x[(size_t)t * BCN + base + 0];
            float4 xb = *(const float4*)&x[(size_t)t * BCN + base + 4];
            float4 xc = *(const float4*)&x[(size_t)t * BCN + base + 8];
            float xs[12] = {xa.x, xa.y, xa.z, xa.w, xb.x, xb.y, xb.z, xb.w,
                            xc.x, xc.y, xc.z, xc.w};
            uint32_t pk[3] = {0, 0, 0};
            uint32_t csum = 0;
            #pragma unroll
            for (int j = 0; j < 12; ++j) {
                v[j] = 0.5 * v[j] + (double)xs[j];
                if (v[j] >= 1.0) {
                    pk[j >> 2] |= 1u << ((j & 3) * 8);
                    csum++;
                    v[j] = 0.0;
                }
            }
            uint32_t* dst = (uint32_t*)&s8[(size_t)t * BCN + base];
            dst[0] = pk[0]; dst[1] = pk[1]; dst[2] = pk[2];
            if (t < 2) c01 += csum << (t * 16);
            else       c23 += csum << ((t - 2) * 16);
        }
        #pragma unroll
        for (int o = 32; o > 0; o >>= 1) {
            c01 += __shfl_xor(c01, o);
            c23 += __shfl_xor(c23, o);
        }
        if (lane == 0) {
            cnt[0 * BC + bc] = (u16)(c01 & 0xFFFF);
            cnt[1 * BC + bc] = (u16)(c01 >> 16);
            cnt[2 * BC + bc] = (u16)(c23 & 0xFFFF);
            cnt[3 * BC + bc] = (u16)(c23 >> 16);
        }
    } else {
        // ---- weight prep ----
        int i = (blockIdx.x - BC / 4) * 256 + threadIdx.x;  // [0, 768*768)
        if (i == 0) *fix_cnt = 0;
        int q1 = __float2int_rn(w1[i] * 512.0f);
        q1 = q1 > 127 ? 127 : (q1 < -127 ? -127 : q1);
        w1q[i] = (int8_t)q1;
        int q16 = __double2int_rn((double)w2[i] * 65536.0);
        int8_t lo = (int8_t)(q16 & 0xFF);
        int hi = (q16 - (int)lo) >> 8;                      // exact split
        w2h[i] = (int8_t)hi;
        w2l[i] = lo;
        w3b[i] = f2b(w3[i]);
    }
}

// ---------------------------------------------------------------------------
// Kernel B (i8) — empirical best (round-5/10 structure):
// y1 = s@w1q^T, y2 = s@(w2h,w2l)^T exact i32; fp64 LIF on y2 with hard
// margin -> fixup list; z = y1*s3 (bf16).
// Block: bc-tile 32 (A rows 128 = 4t x 32), m-tile 64, 4 waves (16 m each).
// K-step 128 (two K=64 subtiles/row). LDS rows 128B, XOR-swizzled (row&7);
// 40KB/buf x2 = 80KB, 2-phase dbuf.
// ---------------------------------------------------------------------------
__global__ __launch_bounds__(256) void y12_kernel(
    const int8_t* __restrict__ s8,
    const int8_t* __restrict__ w1q, const int8_t* __restrict__ w2hb,
    const int8_t* __restrict__ w2lb,
    const u16* __restrict__ cnt,
    u16* __restrict__ z,
    uint32_t* __restrict__ fix_cnt,
    int2* __restrict__ fix_idx, float4* __restrict__ fix_y1)
{
    // per-buffer: A [0,16384) 128x128B; B1 [16384,24576); B2h [24576,32768);
    // B2l [32768,40960)
    __shared__ int8_t lds[2][40960];

    const int tid  = threadIdx.x;
    const int lane = tid & 63;
    const int wid  = tid >> 6;

    // XCD-chunked swizzle: nwg = 2352 = 8 * 294
    const int bid = blockIdx.x;
    const int swz = (bid & 7) * 294 + (bid >> 3);
    const int mb  = swz % (NDIM / 64);
    const int rb  = swz / (NDIM / 64);
    const int m0  = mb * 64;
    const int bc0 = rb * 32;

    // ---- staging: 40 chunks of 1KB (8 rows x 128B); 10 per wave ----
    const int srow  = lane >> 3;                       // row in 8-row chunk
    const int scolB = ((lane & 7) << 4) ^ (srow << 4); // pre-swizzled src byte col
    const int8_t* gp[10];
    int lofs[10];
    #pragma unroll
    for (int c = 0; c < 10; ++c) {
        int chunk = wid * 10 + c;
        const int8_t* g;
        int l;
        if (chunk < 16) {                              // A: 128 rows = t*32+bcl
            int gr = chunk * 8 + srow;
            int t = gr >> 5, bcl = gr & 31;
            g = s8 + ((size_t)(t * BC + bc0 + bcl)) * NDIM + scolB;
            l = chunk * 1024;
        } else if (chunk < 24) {
            int mr = (chunk - 16) * 8 + srow;
            g = w1q + ((size_t)(m0 + mr)) * NDIM + scolB;
            l = 16384 + (chunk - 16) * 1024;
        } else if (chunk < 32) {
            int mr = (chunk - 24) * 8 + srow;
            g = w2hb + ((size_t)(m0 + mr)) * NDIM + scolB;
            l = 24576 + (chunk - 24) * 1024;
        } else {
            int mr = (chunk - 32) * 8 + srow;
            g = w2lb + ((size_t)(m0 + mr)) * NDIM + scolB;
            l = 32768 + (chunk - 32) * 1024;
        }
        gp[c] = g;
        lofs[c] = l;
    }

    // ---- fragment read offsets ----
    const int key = lane & 7;
    const int g4  = lane >> 4;                         // k-group 0..3
    int slotA[2];
    slotA[0] = ((g4       ^ key) << 4);                // ks=0: slots 0..3
    slotA[1] = (((4 | g4) ^ key) << 4);                // ks=1: slots 4..7
    int abase[8];
    #pragma unroll
    for (int t = 0; t < 4; ++t)
        #pragma unroll
        for (int rt = 0; rt < 2; ++rt)
            abase[t * 2 + rt] = (t * 32 + rt * 16 + (lane & 15)) * 128;
    const int bbase = (wid * 16 + (lane & 15)) * 128;

    i32x4 acc1[4][2], acch[4][2], accl[4][2];
    #pragma unroll
    for (int t = 0; t < 4; ++t)
        #pragma unroll
        for (int rt = 0; rt < 2; ++rt) {
            acc1[t][rt] = (i32x4){0, 0, 0, 0};
            acch[t][rt] = (i32x4){0, 0, 0, 0};
            accl[t][rt] = (i32x4){0, 0, 0, 0};
        }

    auto stage = [&](int buf) {
        #pragma unroll
        for (int c = 0; c < 10; ++c) {
            gload16(gp[c], &lds[buf][lofs[c]]);
            gp[c] += 128;
        }
    };
    auto compute = [&](int buf) {
        const int8_t* L = lds[buf];
        #pragma unroll
        for (int ks = 0; ks < 2; ++ks) {
            const int sl = slotA[ks];
            i32x4 b1 = *(const i32x4*)&L[16384 + bbase + sl];
            i32x4 bh = *(const i32x4*)&L[24576 + bbase + sl];
            i32x4 bl = *(const i32x4*)&L[32768 + bbase + sl];
            #pragma unroll
            for (int t = 0; t < 4; ++t)
                #pragma unroll
                for (int rt = 0; rt < 2; ++rt) {
                    i32x4 a = *(const i32x4*)&L[abase[t * 2 + rt] + sl];
                    acc1[t][rt] = MFMAI8(a, b1, acc1[t][rt]);
                    acch[t][rt] = MFMAI8(a, bh, acch[t][rt]);
                    accl[t][rt] = MFMAI8(a, bl, accl[t][rt]);
                }
        }
    };

    // ---- 2-phase dbuf over 6 K-128 tiles ----
    stage(0);
    __syncthreads();
    #pragma unroll
    for (int it = 0; it < 5; ++it) {
        stage((it + 1) & 1);
        compute(it & 1);
        __syncthreads();
    }
    compute(1);

    // ---- epilogue: exact y2_q, fp64 LIF with hard margin, z = y1*s3 ----
    const int mg = m0 + wid * 16 + (lane & 15);
    #pragma unroll
    for (int rt = 0; rt < 2; ++rt) {
        #pragma unroll
        for (int r = 0; r < 4; ++r) {
            const int bcg = bc0 + rt * 16 + (lane >> 4) * 4 + r;
            double v = 0.0, e = 0.0;
            bool flag = false;
            float zv[4], y1v[4];
            #pragma unroll
            for (int t = 0; t < 4; ++t) {
                float y1 = (float)acc1[t][rt][r] * (1.0f / 512.0f);
                y1v[t] = y1;
                double y2 = (double)(acch[t][rt][r] * 256 + accl[t][rt][r])
                            * (1.0 / 65536.0);
                v = 0.5 * v + y2;
                e = 0.5 * e + 7.62939453125e-6 * (double)cnt[t * BC + bcg] + 1e-9;
                double d = v - 1.0;
                flag |= (d <= e && d >= -e);
                if (v >= 1.0) { zv[t] = y1; v = 0.0; e = 0.0; }
                else          { zv[t] = 0.0f; }
            }
            if (flag) {
                uint32_t id = atomicAdd(fix_cnt, 1u);
                if (id < FIX_CAP) {
                    fix_idx[id] = make_int2(bcg, mg);
                    fix_y1[id]  = make_float4(y1v[0], y1v[1], y1v[2], y1v[3]);
                }
            }
            #pragma unroll
            for (int t = 0; t < 4; ++t)
                z[((size_t)(t * BC + bcg)) * NDIM + mg] = f2b(zv[t]);
        }
    }
}

// ---------------------------------------------------------------------------
// Exact fp64 recompute of flagged (bc,m) pairs; one wave per entry.
// 512 blocks (2048 waves) — removes the serial tail between y12 and out.
// ---------------------------------------------------------------------------
__global__ __launch_bounds__(256) void fixup_kernel(
    const int8_t* __restrict__ s8, const float* __restrict__ w2,
    const int2* __restrict__ fix_idx, const float4* __restrict__ fix_y1,
    const uint32_t* __restrict__ fix_cnt, u16* __restrict__ z)
{
    const int lane = threadIdx.x & 63;
    const int wave = (blockIdx.x * 256 + threadIdx.x) >> 6;
    const int nw   = gridDim.x * 4;
    uint32_t n = *fix_cnt;
    if (n > FIX_CAP) n = FIX_CAP;

    for (uint32_t e = wave; e < n; e += nw) {
        const int bc = fix_idx[e].x, m = fix_idx[e].y;
        const float* w2row = w2 + (size_t)m * NDIM;
        double acc[4] = {0.0, 0.0, 0.0, 0.0};
        #pragma unroll
        for (int j = 0; j < NDIM / 64; ++j) {
            int nn = lane + j * 64;
            double wv = (double)w2row[nn];
            #pragma unroll
            for (int t = 0; t < 4; ++t)
                if (s8[((size_t)(t * BC + bc)) * NDIM + nn]) acc[t] += wv;
        }
        #pragma unroll
        for (int o = 32; o > 0; o >>= 1)
            #pragma unroll
            for (int t = 0; t < 4; ++t) acc[t] += __shfl_xor(acc[t], o);
        if (lane == 0) {
            float4 y1 = fix_y1[e];
            float y1a[4] = {y1.x, y1.y, y1.z, y1.w};
            double v = 0.0;
            #pragma unroll
            for (int t = 0; t < 4; ++t) {
                v = 0.5 * v + acc[t];
                u16 zz = 0;
                if (v >= 1.0) { zz = f2b(y1a[t]); v = 0.0; }
                z[((size_t)(t * BC + bc)) * NDIM + m] = zz;
            }
        }
    }
}

// ---------------------------------------------------------------------------
// Kernel C: out[r][m] = sum_n z[r][n]*w3[m][n], bf16 MFMA, fp32 out.
// 128x128 block tile, 4 waves of 64x64. 2-phase dbuf (dense beats sparse:
// r12 measured ballot-sparse ~1.4x slower than this).
// ---------------------------------------------------------------------------
__global__ __launch_bounds__(256, 2) void out_kernel(
    const u16* __restrict__ z, const u16* __restrict__ w3b,
    float* __restrict__ out)
{
    __shared__ u16 lds[2][16384];  // per-buffer 32KB: Zs [0,8192) Ws [8192,16384)

    const int lane = threadIdx.x & 63;
    const int wid  = threadIdx.x >> 6;
    const int rw   = wid >> 1;     // row-half (64 rows)
    const int cw   = wid & 1;      // col-half (64 m)

    const int bid = blockIdx.x;                        // nwg 1176 = 8*147
    const int swz = (bid & 7) * 147 + (bid >> 3);
    const int mb  = swz % (NDIM / 128);
    const int rb  = swz / (NDIM / 128);
    const int m0  = mb * 128;
    const int r0  = rb * 128;

    const int srow  = lane >> 3;
    const int scolE = ((((lane & 7) << 4) ^ ((srow & 7) << 4)) >> 1);
    const u16* gp[8];
    int lofs[8];
    #pragma unroll
    for (int c = 0; c < 8; ++c) {
        int chunk = wid * 8 + c;
        const u16* g;
        if (chunk < 16) {
            int gr = chunk * 8 + srow;
            g = z + ((size_t)(r0 + gr)) * NDIM + scolE;
        } else {
            int mr = (chunk - 16) * 8 + srow;
            g = w3b + ((size_t)(m0 + mr)) * NDIM + scolE;
        }
        gp[c] = g;
        lofs[c] = chunk * 512;
    }

    const int swzb = (lane & 7) << 4;
    const int cb   = (lane >> 4) << 4;
    const int colE0 = ((cb     ) ^ swzb) >> 1;
    const int colE1 = ((cb | 64) ^ swzb) >> 1;

    f32x4 acc[4][4];               // [rt][cf]
    #pragma unroll
    for (int rt = 0; rt < 4; ++rt)
        #pragma unroll
        for (int cf = 0; cf < 4; ++cf) acc[rt][cf] = (f32x4){0.f, 0.f, 0.f, 0.f};

    auto stage = [&](int buf) {
        #pragma unroll
        for (int c = 0; c < 8; ++c) {
            gload16(gp[c], &lds[buf][lofs[c]]);
            gp[c] += 64;
        }
    };
    auto compute = [&](int buf) {
        const u16* L = lds[buf];
        #pragma unroll
        for (int k2i = 0; k2i < 2; ++k2i) {
            const int ce = k2i ? colE1 : colE0;
            bf16x8 bw[4];
            #pragma unroll
            for (int cf = 0; cf < 4; ++cf)
                bw[cf] = *(const bf16x8*)&L[8192 + (cw * 64 + cf * 16 + (lane & 15)) * 64 + ce];
            #pragma unroll
            for (int rt = 0; rt < 4; ++rt) {
                bf16x8 az = *(const bf16x8*)&L[(rw * 64 + rt * 16 + (lane & 15)) * 64 + ce];
                #pragma unroll
                for (int cf = 0; cf < 4; ++cf)
                    acc[rt][cf] = MFMA16(az, bw[cf], acc[rt][cf]);
            }
        }
    };

    stage(0);
    __syncthreads();
    for (int it = 0; it < 11; ++it) {
        stage((it + 1) & 1);
        compute(it & 1);
        __syncthreads();
    }
    compute(1);

    #pragma unroll
    for (int rt = 0; rt < 4; ++rt)
        #pragma unroll
        for (int cf = 0; cf < 4; ++cf)
            #pragma unroll
            for (int r = 0; r < 4; ++r)
                out[((size_t)(r0 + rw * 64 + rt * 16 + (lane >> 4) * 4 + r)) * NDIM
                    + m0 + cw * 64 + cf * 16 + (lane & 15)] = acc[rt][cf][r];
}

// ---------------------------------------------------------------------------
extern "C" void kernel_launch(void* const* d_in, const int* in_sizes, int n_in,
                              void* d_out, int out_size, void* d_ws, size_t ws_size,
                              hipStream_t stream) {
    const float* x  = (const float*)d_in[0];
    const float* w1 = (const float*)d_in[1];
    const float* w2 = (const float*)d_in[2];
    const float* w3 = (const float*)d_in[3];
    float* out = (float*)d_out;

    char* ws = (char*)d_ws;
    int8_t*   s8      = (int8_t*)(ws);                    // 19,267,584
    u16*      z       = (u16*)(ws + 19267584);            // 38,535,168
    int8_t*   w1q     = (int8_t*)(ws + 57802752);
    int8_t*   w2h     = (int8_t*)(ws + 58392576);
    int8_t*   w2l     = (int8_t*)(ws + 58982400);
    u16*      w3b     = (u16*)(ws + 59572224);
    u16*      cnt     = (u16*)(ws + 60751872);
    uint32_t* fix_cnt = (uint32_t*)(ws + 60802048);
    int2*     fix_idx = (int2*)(ws + 60802112);
    float4*   fix_y1  = (float4*)(ws + 61326400);

    front_kernel<<<BC / 4 + (NDIM * NDIM) / 256, 256, 0, stream>>>(
        x, w1, w2, w3, s8, cnt, w1q, w2h, w2l, w3b, fix_cnt);
    y12_kernel<<<(BC / 32) * (NDIM / 64), 256, 0, stream>>>(s8, w1q, w2h, w2l,
                                                            cnt, z, fix_cnt,
                                                            fix_idx, fix_y1);
    fixup_kernel<<<512, 256, 0, stream>>>(s8, w2, fix_idx, fix_y1, fix_cnt, z);
    out_kernel<<<(TBC / 128) * (NDIM / 128), 256, 0, stream>>>(z, w3b, out);
}